// Round 1
// baseline (96.735 us; speedup 1.0000x reference)
//
#include <hip/hip_runtime.h>

// HeteroLinear fused forward on gfx950.
// out[i] = x[i] @ W[type_vec[i]] + b[type_vec[i]]
// N=131072, IN=OUT=256, T=8, type_vec sorted.
// Strategy: bf16 MFMA (16x16x32), x staged to LDS bf16 (swizzled), weights
// pre-transposed to bf16 [T][N][K] in d_ws, B-fragments straight from L2.

#define N_ROWS 131072
#define KDIM 256
#define NDIM 256

typedef __attribute__((ext_vector_type(8))) short short8;
typedef __attribute__((ext_vector_type(4))) short short4v;
typedef __attribute__((ext_vector_type(4))) float f32x4;
typedef __attribute__((ext_vector_type(4))) float flt4;

__device__ inline unsigned short f2bf(float f) {
    unsigned int u = __float_as_uint(f);
    u += 0x7FFFu + ((u >> 16) & 1u);   // round-to-nearest-even
    return (unsigned short)(u >> 16);
}

// wT[t][n][k] = bf16(w[t][k][n]) ; grid = T*256 blocks, 256 threads
__global__ void prep_weights(const float* __restrict__ w,
                             unsigned short* __restrict__ wT) {
    int t = blockIdx.x >> 8;
    int n = blockIdx.x & 255;
    int k = threadIdx.x;
    wT[(((size_t)t << 8) + n) * 256 + k] = f2bf(w[(((size_t)t << 8) + k) * 256 + n]);
}

__global__ __launch_bounds__(256) void hetero_gemm(
        const float* __restrict__ x, const int* __restrict__ tv,
        const unsigned short* __restrict__ wT, const float* __restrict__ bias,
        float* __restrict__ out) {
    // A tile: 64 rows x 256 k, bf16, XOR-swizzled (half-index ^= (row&7)<<3)
    __shared__ short Alds[64 * 256];
    __shared__ int types[64];

    const int tid  = threadIdx.x;
    const int lane = tid & 63;
    const int wv   = tid >> 6;          // wave 0..3 -> cols wv*64..wv*64+63
    const int r0   = blockIdx.x * 64;

    if (tid < 64) types[tid] = tv[r0 + tid];

    // ---- stage x (fp32) -> Alds (bf16, swizzled) ----
    {
        const flt4* xv = (const flt4*)(x + (size_t)r0 * KDIM);
        #pragma unroll
        for (int i = 0; i < 16; ++i) {
            int idx = i * 256 + tid;      // 0..4095 float4s (64 rows * 64/row)
            int row = idx >> 6;
            int kq  = idx & 63;           // k = kq*4
            flt4 v = xv[idx];
            short4v s;
            s[0] = (short)f2bf(v[0]);
            s[1] = (short)f2bf(v[1]);
            s[2] = (short)f2bf(v[2]);
            s[3] = (short)f2bf(v[3]);
            int h = (row << 8) + (kq << 2);
            h ^= (row & 7) << 3;
            *(short4v*)&Alds[h] = s;
        }
    }
    __syncthreads();

    const int tmin = types[0];    // sorted -> block min/max at ends
    const int tmax = types[63];

    const int cl = lane & 15;     // row-in-frag (A) / col-in-frag (B, C)
    const int kg = lane >> 4;     // k-group (8 elems each)

    for (int t = tmin; t <= tmax; ++t) {
        const unsigned short* Bt = wT + (size_t)t * (KDIM * NDIM);

        f32x4 zero = {0.0f, 0.0f, 0.0f, 0.0f};
        f32x4 acc[4][4];
        #pragma unroll
        for (int m = 0; m < 4; ++m)
            #pragma unroll
            for (int n = 0; n < 4; ++n)
                acc[m][n] = zero;

        #pragma unroll
        for (int ks = 0; ks < 8; ++ks) {
            const int k0 = ks * 32;
            short8 a[4], b[4];
            #pragma unroll
            for (int m = 0; m < 4; ++m) {
                int row = m * 16 + cl;
                int h = (row << 8) + k0 + kg * 8;
                h ^= (row & 7) << 3;
                a[m] = *(const short8*)&Alds[h];
            }
            #pragma unroll
            for (int n = 0; n < 4; ++n) {
                int col = wv * 64 + n * 16 + cl;
                b[n] = *(const short8*)(Bt + col * KDIM + k0 + kg * 8);
            }
            #pragma unroll
            for (int m = 0; m < 4; ++m)
                #pragma unroll
                for (int n = 0; n < 4; ++n)
                    acc[m][n] = __builtin_amdgcn_mfma_f32_16x16x32_bf16(
                        a[m], b[n], acc[m][n], 0, 0, 0);
        }

        // ---- epilogue: bias + predicated store (row's type == t) ----
        float bv[4];
        #pragma unroll
        for (int n = 0; n < 4; ++n)
            bv[n] = bias[t * NDIM + wv * 64 + n * 16 + cl];

        #pragma unroll
        for (int m = 0; m < 4; ++m) {
            int rbase = m * 16 + kg * 4;
            #pragma unroll
            for (int j = 0; j < 4; ++j) {
                int r = rbase + j;
                if (types[r] == t) {
                    float* orow = out + (size_t)(r0 + r) * NDIM + wv * 64 + cl;
                    #pragma unroll
                    for (int n = 0; n < 4; ++n)
                        orow[n * 16] = acc[m][n][j] + bv[n];
                }
            }
        }
    }
}

extern "C" void kernel_launch(void* const* d_in, const int* in_sizes, int n_in,
                              void* d_out, int out_size, void* d_ws, size_t ws_size,
                              hipStream_t stream) {
    const float* x    = (const float*)d_in[0];
    const int*   tv   = (const int*)d_in[1];
    const float* w    = (const float*)d_in[2];
    const float* bias = (const float*)d_in[3];
    float* out = (float*)d_out;
    unsigned short* wT = (unsigned short*)d_ws;   // 8*256*256*2 = 1 MiB

    prep_weights<<<dim3(8 * 256), dim3(256), 0, stream>>>(w, wT);
    hetero_gemm<<<dim3(N_ROWS / 64), dim3(256), 0, stream>>>(x, tv, wT, bias, out);
}